// Round 7
// baseline (128.396 us; speedup 1.0000x reference)
//
#include <hip/hip_runtime.h>
#include <math.h>

#define BATCH 16384
#define NW 10
#define DEPTH 2

// ============================================================================
// Two regular kernels, both spill-free (max ~70 VGPR/thread):
//  k1: 16 blocks x 64 (one wave per encoded basis column a): simulate
//      u_a = U |a<<6> with the verified register/shuffle simulator, write
//      u[a][0..1024) to ws (131 KB).
//  kB: 64 blocks x 256: each block redundantly computes the 136 symmetric
//      pair reductions C_w[a][b] = Re(i^(popc(a)-popc(b)) sum_i sign_w(i)
//      conj(u_a_i) u_b_i) from L2-hot u (one pair per wave per step), builds
//      the 81x10 trig-basis table K in LDS, then evaluates 256 batch elems:
//      z_w(x) = sum_t K_w[t] * prod_q {1,cos x_q,sin x_q}_(t_q).
// ============================================================================

// ---- kernel 1: one wave = one basis column -----------------------------
__global__ __launch_bounds__(64, 1) void k1_basis(const float* __restrict__ theta,
                                                  float2* __restrict__ u)
{
    const int lane = threadIdx.x;        // one wave per block
    const int a = blockIdx.x;            // 0..15

    float re[16], im[16];
#pragma unroll
    for (int r = 0; r < 16; ++r) { re[r] = 0.0f; im[r] = 0.0f; }
    if (lane == 0) re[a] = 1.0f;         // |a<<6>

    float ct[NW], st_[NW];
#pragma unroll
    for (int w = 0; w < NW; ++w) {
        const float h = 0.5f * theta[w];
        ct[w] = __cosf(h); st_[w] = __sinf(h);
    }

#pragma unroll 1
    for (int d = 0; d < DEPTH; ++d) {
#pragma unroll
        for (int w = 0; w < 4; ++w) {            // RX on register wires
            const float c = ct[w], s = st_[w];
            const int m = 8 >> w;
#pragma unroll
            for (int r = 0; r < 16; ++r) {
                if (!(r & m)) {
                    const int r1 = r | m;
                    const float a0r = re[r],  a0i = im[r];
                    const float a1r = re[r1], a1i = im[r1];
                    re[r]  = c * a0r + s * a1i;
                    im[r]  = c * a0i - s * a1r;
                    re[r1] = c * a1r + s * a0i;
                    im[r1] = c * a1i - s * a0r;
                }
            }
        }
#pragma unroll
        for (int w = 4; w < 10; ++w) {           // RX on lane wires
            const float c = ct[w], s = st_[w];
            const int lm = 32 >> (w - 4);
#pragma unroll
            for (int r = 0; r < 16; ++r) {
                const float pr = __shfl_xor(re[r], lm, 64);
                const float pi = __shfl_xor(im[r], lm, 64);
                re[r] = c * re[r] + s * pi;
                im[r] = c * im[r] - s * pr;
            }
        }
        // ring CNOTs (0,1)(1,2)(2,3): register swaps
#pragma unroll
        for (int w = 0; w < 3; ++w) {
            const int cm = 8 >> w, tm = 8 >> (w + 1);
#pragma unroll
            for (int r = 0; r < 16; ++r) {
                if ((r & cm) && !(r & tm)) {
                    const int r2 = r | tm;
                    float t;
                    t = re[r]; re[r] = re[r2]; re[r2] = t;
                    t = im[r]; im[r] = im[r2]; im[r2] = t;
                }
            }
        }
        // (3,4): odd registers swap lanes across bit5
#pragma unroll
        for (int r = 0; r < 16; ++r) {
            if (r & 1) {
                re[r] = __shfl_xor(re[r], 32, 64);
                im[r] = __shfl_xor(im[r], 32, 64);
            }
        }
        // (4,5)..(8,9): lane-bit CNOTs
#pragma unroll
        for (int w = 4; w < 9; ++w) {
            const int cm = 32 >> (w - 4), tm = 32 >> (w - 3);
            const bool ctl = (lane & cm) != 0;
#pragma unroll
            for (int r = 0; r < 16; ++r) {
                const float pr = __shfl_xor(re[r], tm, 64);
                const float pi = __shfl_xor(im[r], tm, 64);
                re[r] = ctl ? pr : re[r];
                im[r] = ctl ? pi : im[r];
            }
        }
        // (9,0): lane-bit0 controlled register-bit3 swap
        {
            const bool ctl = (lane & 1) != 0;
#pragma unroll
            for (int r = 0; r < 8; ++r) {
                const float t0r = re[r], t1r = re[r + 8];
                const float t0i = im[r], t1i = im[r + 8];
                re[r]     = ctl ? t1r : t0r;
                re[r + 8] = ctl ? t0r : t1r;
                im[r]     = ctl ? t1i : t0i;
                im[r + 8] = ctl ? t0i : t1i;
            }
        }
    }

#pragma unroll
    for (int r = 0; r < 16; ++r)
        u[a * 1024 + (r << 6) + lane] = make_float2(re[r], im[r]);
}

// ---- kernel B: gram (per block, redundant) + K + per-batch eval --------
__global__ __launch_bounds__(256) void kB_eval(const float* __restrict__ x,
                                               const float2* __restrict__ u,
                                               float* __restrict__ out)
{
    __shared__ float sC[256 * 12];
    __shared__ float sK[81 * 12];

    const int lane = threadIdx.x & 63;
    const int wv   = threadIdx.x >> 6;       // 0..3 (wave-uniform)

    // ---- gram phase: each wave handles pairs p = wv, wv+4, ... ----------
    for (int p = wv; p < 136; p += 4) {
        // map p -> (a<=b), wave-uniform scalar loop
        int t = p, a = 0;
        while (t >= 16 - a) { t -= 16 - a; ++a; }
        const int b = a + t;

        const int pp = (__popc(a) - __popc(b)) & 3;
        const bool odd = (pp & 1) != 0;

        float acc0 = 0.0f, acc1 = 0.0f, acc2 = 0.0f, acc3 = 0.0f, accT = 0.0f;
#pragma unroll
        for (int r = 0; r < 16; ++r) {
            const float2 ua = u[a * 1024 + (r << 6) + lane];
            const float2 ub = u[b * 1024 + (r << 6) + lane];
            const float vr = ua.x * ub.x + ua.y * ub.y;   // Re(conj(ua)*ub)
            const float vi = ua.x * ub.y - ua.y * ub.x;   // Im
            const float v  = odd ? vi : vr;
            acc0 += (r & 8) ? -v : v;     // wire 0 (bit 3 of r)
            acc1 += (r & 4) ? -v : v;
            acc2 += (r & 2) ? -v : v;
            acc3 += (r & 1) ? -v : v;
            accT += v;
        }
        float red[10];
        red[0] = acc0; red[1] = acc1; red[2] = acc2; red[3] = acc3;
        red[4] = (lane & 32) ? -accT : accT;   // wire 4 (lane bit 5)
        red[5] = (lane & 16) ? -accT : accT;
        red[6] = (lane &  8) ? -accT : accT;
        red[7] = (lane &  4) ? -accT : accT;
        red[8] = (lane &  2) ? -accT : accT;
        red[9] = (lane &  1) ? -accT : accT;

#pragma unroll
        for (int k = 0; k < 10; ++k) {
            float v = red[k];
#pragma unroll
            for (int ofs = 32; ofs >= 1; ofs >>= 1)
                v += __shfl_xor(v, ofs, 64);
            red[k] = v;
        }

        if (lane == 0) {
            // C = Re(i^p S): p=0 -> +Sr, 1 -> -Si, 2 -> -Sr, 3 -> +Si
            const float sg = (pp == 1 || pp == 2) ? -1.0f : 1.0f;
#pragma unroll
            for (int w = 0; w < NW; ++w) {
                const float val = sg * red[w];
                sC[(a * 16 + b) * 12 + w] = val;
                sC[(b * 16 + a) * 12 + w] = val;   // C symmetric
            }
        }
    }
    __syncthreads();

    // ---- K phase: K_w[t] = (1/16) sum over 16 signed C entries ----------
    for (int idx = threadIdx.x; idx < 810; idx += 256) {
        const int t = idx / 10, w = idx - 10 * t;
        int d0 = t / 27, r0 = t - d0 * 27;
        int d1 = r0 / 9, r1 = r0 - d1 * 9;
        int d2 = r1 / 3, d3 = r1 - d2 * 3;
        const int d[4] = { d0, d1, d2, d3 };

        float s = 0.0f;
#pragma unroll
        for (int e = 0; e < 16; ++e) {
            int aa = 0, bb = 0; float sgn = 1.0f;
#pragma unroll
            for (int qq = 0; qq < 4; ++qq) {
                const int eq = (e >> (3 - qq)) & 1;
                int aq, bq;
                if (d[qq] == 2) { aq = eq; bq = 1 - eq; }
                else {
                    aq = eq; bq = eq;
                    if (d[qq] == 1 && eq) sgn = -sgn;
                }
                aa |= aq << (3 - qq);
                bb |= bq << (3 - qq);
            }
            s += sgn * sC[(aa * 16 + bb) * 12 + w];
        }
        sK[t * 12 + w] = s * 0.0625f;
    }
    __syncthreads();

    // ---- eval phase: one thread per batch element -----------------------
    const int bidx = blockIdx.x * 256 + threadIdx.x;   // 0..16383
    const float4 xv = ((const float4*)x)[bidx];

    float s0, c0, s1, c1, s2, c2, s3, c3;
    __sincosf(xv.x, &s0, &c0);
    __sincosf(xv.y, &s1, &c1);
    __sincosf(xv.z, &s2, &c2);
    __sincosf(xv.w, &s3, &c3);

    const float b0[3] = { 1.0f, c0, s0 };
    const float b1[3] = { 1.0f, c1, s1 };
    const float b2[3] = { 1.0f, c2, s2 };
    const float b3[3] = { 1.0f, c3, s3 };
    float B01[9], B23[9];
#pragma unroll
    for (int i = 0; i < 3; ++i)
#pragma unroll
        for (int j = 0; j < 3; ++j) {
            B01[i * 3 + j] = b0[i] * b1[j];
            B23[i * 3 + j] = b2[i] * b3[j];
        }

    float z[NW];
#pragma unroll
    for (int w = 0; w < NW; ++w) z[w] = 0.0f;

#pragma unroll
    for (int t01 = 0; t01 < 9; ++t01) {
#pragma unroll
        for (int t23 = 0; t23 < 9; ++t23) {
            const float P = B01[t01] * B23[t23];
            const float* base = &sK[(t01 * 9 + t23) * 12];
            const float4 q0 = *(const float4*)(base + 0);
            const float4 q1 = *(const float4*)(base + 4);
            const float4 q2 = *(const float4*)(base + 8);
            z[0] = fmaf(P, q0.x, z[0]);
            z[1] = fmaf(P, q0.y, z[1]);
            z[2] = fmaf(P, q0.z, z[2]);
            z[3] = fmaf(P, q0.w, z[3]);
            z[4] = fmaf(P, q1.x, z[4]);
            z[5] = fmaf(P, q1.y, z[5]);
            z[6] = fmaf(P, q1.z, z[6]);
            z[7] = fmaf(P, q1.w, z[7]);
            z[8] = fmaf(P, q2.x, z[8]);
            z[9] = fmaf(P, q2.y, z[9]);
        }
    }

    float2* po = (float2*)(out + bidx * NW);
    po[0] = make_float2(z[0], z[1]);
    po[1] = make_float2(z[2], z[3]);
    po[2] = make_float2(z[4], z[5]);
    po[3] = make_float2(z[6], z[7]);
    po[4] = make_float2(z[8], z[9]);
}

extern "C" void kernel_launch(void* const* d_in, const int* in_sizes, int n_in,
                              void* d_out, int out_size, void* d_ws, size_t ws_size,
                              hipStream_t stream) {
    const float* x     = (const float*)d_in[0];
    const float* theta = (const float*)d_in[1];
    float* out = (float*)d_out;
    float2* u  = (float2*)d_ws;          // 16*1024*8 = 131072 B

    hipLaunchKernelGGL(k1_basis, dim3(16), dim3(64),  0, stream, theta, u);
    hipLaunchKernelGGL(kB_eval,  dim3(BATCH / 256), dim3(256), 0, stream, x, u, out);
}